// Round 9
// baseline (200.575 us; speedup 1.0000x reference)
//
#include <hip/hip_runtime.h>
#include <hip/hip_bf16.h>
#include <math.h>

// Problem constants
#define BB 4
#define TT 2048
#define CC 1024
#define HH 16
#define DD 64
#define WW 256
#define MM (BB*TT)   // 8192 rows
#define NX (MM*CC)
#define NQ (3*CC*CC)
#define NP (CC*CC)

typedef __bf16 bf16x8 __attribute__((ext_vector_type(8)));
typedef __bf16 bf16x4 __attribute__((ext_vector_type(4)));
typedef float  f32x4  __attribute__((ext_vector_type(4)));

// async global->LDS 16B. LDS dest: wave-uniform base, HW adds lane*16.
// GLOBAL SOURCE IS PER-LANE: caller must add lane*16B for a contiguous
// stage (r17 lesson).
__device__ __forceinline__ void async_cp16(const void* g, void* l) {
  __builtin_amdgcn_global_load_lds(
      (const __attribute__((address_space(1))) void*)g,
      (__attribute__((address_space(3))) void*)l, 16, 0, 0);
}

__device__ __forceinline__ unsigned short f2bf(float v) {
  __hip_bfloat16 h = __float2bfloat16(v);
  return *(unsigned short*)&h;
}

// Weight chunk-image pack offset: layout
//   [panel p = n>>7][ktile kt = k>>6][chunk = kc*2+half][lane = n&63][ko = k&7]
// gemm stage cp16 #idx reads 1KB CONTIGUOUS (lane l -> +16B*l) at
// ((p*16+kt)*16+idx)*512.
__device__ __forceinline__ size_t wpk_off(int n, int k) {
  return ((((size_t)(n >> 7) * 16 + (k >> 6)) * 16) +
          (((k >> 3) & 7) * 2 + ((n >> 6) & 1))) * 512 +
         (size_t)(n & 63) * 8 + (k & 7);
}

// ---------------------------------------------------------------------------
// prep: fused (a) weight fp32->bf16 convert + chunk-image pack,
// (b) x convert+pack into MFMA A-fragment-major layout.
// ---------------------------------------------------------------------------
__global__ __launch_bounds__(256)
void prep(const float* __restrict__ x,
          const float* __restrict__ wq,
          const float* __restrict__ wp,
          unsigned short* __restrict__ wpk,
          unsigned short* __restrict__ Apk) {
  const int p = blockIdx.x;
  const int tid = threadIdx.x;
  if (p < 4096) {                       // ---- weight convert + pack
    int i = (p * 256 + tid) * 4;
    const float* src; unsigned short* dst; int n, k;
    if (i < NQ) { src = wq + i; n = i >> 10; k = i & 1023; dst = wpk; }
    else {
      int j = i - NQ;
      src = wp + j; n = j >> 10; k = j & 1023; dst = wpk + NQ;
    }
    float4 v = *(const float4*)src;
    size_t off = wpk_off(n, k);         // k%4==0 -> 4 shorts contiguous
    dst[off + 0] = f2bf(v.x);
    dst[off + 1] = f2bf(v.y);
    dst[off + 2] = f2bf(v.z);
    dst[off + 3] = f2bf(v.w);
    return;
  }
  // ---- x convert + pack (64 rows x 64 k per block)
  __shared__ __align__(16) unsigned short tile[64 * 72]; // stride 144B
  const int pid = p - 4096;
  const int bm = pid & 127;
  const int bk = pid >> 7;
  const int tr = tid >> 4;
  const int tc = (tid & 15) * 4;
#pragma unroll
  for (int i = 0; i < 4; i++) {
    int row = i * 16 + tr;
    float4 v = *(const float4*)&x[(size_t)(bm * 64 + row) * 1024 + bk * 64 + tc];
    tile[row * 72 + tc + 0] = f2bf(v.x);
    tile[row * 72 + tc + 1] = f2bf(v.y);
    tile[row * 72 + tc + 2] = f2bf(v.z);
    tile[row * 72 + tc + 3] = f2bf(v.w);
  }
  __syncthreads();
  const int w = tid >> 6, lane = tid & 63;
  const int quad = lane >> 4, l15 = lane & 15;
#pragma unroll
  for (int f = 0; f < 2; f++) {
    bf16x8 fr = *(const bf16x8*)&tile[(w * 16 + l15) * 72 + f * 32 + quad * 8];
    *(bf16x8*)&Apk[(((size_t)(bm * 4 + w) * 32) + bk * 2 + f) * 512 + lane * 8] = fr;
  }
}

// ---------------------------------------------------------------------------
// QKV GEMM (round 22 = REVERT to r18, proven 57.8-58.0us across 3 runs):
// counted-vmcnt per 64-K step, 3-deep stage prefetch, chunk-image pack.
// r21's fine-phase (8 barriers/step) regressed qkv to 78us -- with
// 64 MFMA/step the loop was already near its structure's best and the
// barrier convoy swamped it (4-wave blocks lack m201's 8-wave
// role-split). Fine-phase stays ONLY in proj (32 MFMA/step, overhead-
// dominated, gained ~22us).
// ---------------------------------------------------------------------------
__global__ __launch_bounds__(256, 2)
void gemm_qkv(const unsigned short* __restrict__ Apk,
              const unsigned short* __restrict__ Bw,
              unsigned short* __restrict__ Qh,
              unsigned short* __restrict__ Kh,
              unsigned short* __restrict__ Vt) {
  __shared__ __align__(16) unsigned short Bs[4][8192]; // 4 x 16 KB, BK=64

  const int id   = blockIdx.x;
  const int xcd  = id & 7;
  const int slot = id >> 3;        // 0..95
  const int mloc = slot / 24;      // 0..3   (XCD-local m-block)
  const int nloc = slot % 24;      // 0..23  (n-panels stream over L2-hot A)
  const int m0 = (xcd * 4 + mloc) * 256;
  const int n0 = nloc * 128;

  const int tid  = threadIdx.x;
  const int w    = tid >> 6;       // 0..3: row-block of 64
  const int lane = tid & 63;
  const int quad = lane >> 4;
  const int l15  = lane & 15;

  f32x4 acc[4][8];
#pragma unroll
  for (int i = 0; i < 4; i++)
#pragma unroll
    for (int j = 0; j < 8; j++) acc[i][j] = (f32x4)0.0f;

  const unsigned short* abase =
      Apk + ((size_t)((m0 >> 4) + w * 4) * 32) * 512 + lane * 8;

  // packed-panel base: panel p = n0>>7, 16 ktiles x 16 chunks x 512
  const unsigned short* wb = Bw + (size_t)(n0 >> 7) * (16 * 16 * 512);

  // BK=64 stage: 16 KB/buffer -> 4 cp16/wave, contiguous 1KB each
  auto stageB = [&](int kt, unsigned short* bs) {
#pragma unroll
    for (int i = 0; i < 4; i++) {
      int idx = w + 4 * i;         // 0..15
      async_cp16(wb + ((size_t)kt * 16 + idx) * 512 + lane * 8,
                 &bs[idx * 512]);
    }
  };

  bf16x8 Af[3][4];                 // depth-2 A prefetch ring (L2-hit ~200cyc)
  auto loadA = [&](int g, bf16x8* fr) {
#pragma unroll
    for (int tm = 0; tm < 4; tm++)
      fr[tm] = *(const bf16x8*)(abase + ((size_t)(tm * 32 + g)) * 512);
  };

  // prologue: A for g=0,1; stage buffers 0..2; one-time full drain
  loadA(0, Af[0]);
  loadA(1, Af[1]);
  stageB(0, Bs[0]);
  stageB(1, Bs[1]);
  stageB(2, Bs[2]);
  asm volatile("s_waitcnt vmcnt(0)" ::: "memory");
  __builtin_amdgcn_sched_barrier(0);
  asm volatile("s_barrier" ::: "memory");

#pragma unroll
  for (int s = 0; s < 16; s++) {
    const unsigned short* bs = Bs[s & 3];
    if (s + 3 < 16) stageB(s + 3, Bs[(s + 3) & 3]); // 3-deep prefetch
#pragma unroll
    for (int sub = 0; sub < 2; sub++) {
      const int g = s * 2 + sub;
      if (g + 2 < 32) loadA(g + 2, Af[(g + 2) % 3]);
      const bf16x8* af = Af[g % 3];
      __builtin_amdgcn_s_setprio(1);
#pragma unroll
      for (int tn = 0; tn < 8; tn++) {
        bf16x8 bfv = *(const bf16x8*)
            &bs[(sub * 4 + quad) * 1024 + (tn * 16 + l15) * 8];
#pragma unroll
        for (int tm = 0; tm < 4; tm++)
          acc[tm][tn] = __builtin_amdgcn_mfma_f32_16x16x32_bf16(
              af[tm], bfv, acc[tm][tn], 0, 0, 0);
      }
      __builtin_amdgcn_s_setprio(0);
    }
    // publish stage(s+1) retirement (counted; stages s+2,s+3 + A stay
    // in flight across the barrier), drain own ds_reads of Bs[s&3].
    asm volatile("s_waitcnt vmcnt(16) lgkmcnt(0)" ::: "memory");
    __builtin_amdgcn_sched_barrier(0);
    asm volatile("s_barrier" ::: "memory");
  }

  const int t3 = n0 >> 10;              // block-uniform: 0=Q,1=K,2=V
  if (t3 == 0) {
    // ---- Q scatter to head-major [b*h][t][d] (attn reads directly)
#pragma unroll
    for (int tm = 0; tm < 4; tm++)
#pragma unroll
      for (int tn = 0; tn < 8; tn++) {
        int colb = n0 + tn * 16;
        int hh = (colb >> 6) & 15;
        int dd = (colb & 63) + l15;
#pragma unroll
        for (int r = 0; r < 4; r++) {
          int row = m0 + w * 64 + tm * 16 + quad * 4 + r;
          int b = row >> 11, tt = row & 2047;
          Qh[((size_t)((b * 16 + hh) * 2048 + tt)) * 64 + dd] =
              f2bf(acc[tm][tn][r] * 0.125f);   // 1/sqrt(64)
        }
      }
  } else if (t3 == 1) {
    // ---- K scatter to chunk-image Kpk[bh][tc][d-octet][tin][8]
#pragma unroll
    for (int tm = 0; tm < 4; tm++)
#pragma unroll
      for (int tn = 0; tn < 8; tn++) {
        int colb = n0 + tn * 16;
        int hh = (colb >> 6) & 15;
        int dd = (colb & 63) + l15;
#pragma unroll
        for (int r = 0; r < 4; r++) {
          int row = m0 + w * 64 + tm * 16 + quad * 4 + r;
          int b = row >> 11, tt = row & 2047;
          Kh[((((size_t)(b * 16 + hh) * 32 + (tt >> 6)) * 8 + (dd >> 3)) * 512)
             + (tt & 63) * 8 + (dd & 7)] = f2bf(acc[tm][tn][r]);
        }
      }
  } else {
    // ---- V: per-wave LDS transpose -> Vpk[bh][tc][t-octet][d][8t]
    unsigned short* T = &Bs[0][0] + w * 4608;            // 64x72 tile/wave
    const int b    = (m0 + w * 64) >> 11;
    const int tc_g = ((m0 & 2047) >> 6) + w;
    const int h0   = (n0 >> 6) & 15;
#pragma unroll
    for (int hp = 0; hp < 2; hp++) {
      // T[d][t^]: T[d*72 + t^] = V value at (t = chunk*64 + t^, d)
#pragma unroll
      for (int tnl = 0; tnl < 4; tnl++)
#pragma unroll
        for (int tm = 0; tm < 4; tm++)
#pragma unroll
          for (int r = 0; r < 4; r++)
            T[(tnl * 16 + l15) * 72 + tm * 16 + quad * 4 + r] =
                f2bf(acc[tm][hp * 4 + tnl][r]);
      asm volatile("s_waitcnt lgkmcnt(0)" ::: "memory");  // wave-private
      const size_t base =
          ((size_t)((b * 16 + h0 + hp) * 32 + tc_g)) * 4096;
#pragma unroll
      for (int j = 0; j < 8; j++) {                       // t-octet
        bf16x8 v = *(const bf16x8*)&T[lane * 72 + j * 8]; // d=lane
        *(bf16x8*)&Vt[base + (size_t)j * 512 + lane * 8] = v; // 1KB contig
      }
    }
  }
}

// ---------------------------------------------------------------------------
// Proj GEMM (r21 fine-phase, KEPT: rest-of-pipeline gained ~22us).
// 32 MFMA/step made the old schedule overhead-dominated; the per-phase
// {ds_read || stage || MFMA} interleave fixed it.
// ---------------------------------------------------------------------------
__global__ __launch_bounds__(256, 2)
void gemm_proj(const unsigned short* __restrict__ Apk,
               const unsigned short* __restrict__ Bw,
               float* __restrict__ Co) {
  __shared__ __align__(16) unsigned short Bs[4][8192];

  const int id   = blockIdx.x;
  const int xcd  = id & 7;
  const int slot = id >> 3;        // 0..63
  const int mloc = slot >> 3;      // 0..7
  const int nloc = slot & 7;       // 0..7
  const int m0 = (xcd * 8 + mloc) * 128;
  const int n0 = nloc * 128;

  const int tid  = threadIdx.x;
  const int w    = tid >> 6;
  const int lane = tid & 63;
  const int quad = lane >> 4;
  const int l15  = lane & 15;

  f32x4 acc[2][8];
#pragma unroll
  for (int i = 0; i < 2; i++)
#pragma unroll
    for (int j = 0; j < 8; j++) acc[i][j] = (f32x4)0.0f;

  const unsigned short* abase =
      Apk + ((size_t)((m0 >> 4) + w * 2) * 32) * 512 + lane * 8;

  const unsigned short* wb = Bw + (size_t)(n0 >> 7) * (16 * 16 * 512);

  auto stageB = [&](int kt, unsigned short* bs) {
#pragma unroll
    for (int i = 0; i < 4; i++) {
      int idx = w + 4 * i;
      async_cp16(wb + ((size_t)kt * 16 + idx) * 512 + lane * 8,
                 &bs[idx * 512]);
    }
  };

  bf16x8 Af[3][2];                 // depth-2 A prefetch ring
  auto loadA = [&](int g, bf16x8* fr) {
#pragma unroll
    for (int tm = 0; tm < 2; tm++)
      fr[tm] = *(const bf16x8*)(abase + ((size_t)(tm * 32 + g)) * 512);
  };

  stageB(0, Bs[0]);
  stageB(1, Bs[1]);
  stageB(2, Bs[2]);
  loadA(0, Af[0]);
  loadA(1, Af[1]);
  asm volatile("s_waitcnt vmcnt(12)" ::: "memory");
  __builtin_amdgcn_sched_barrier(0);
  __builtin_amdgcn_s_barrier();

#pragma unroll
  for (int s = 0; s < 16; s++) {
    const unsigned short* bs = Bs[s & 3];
    unsigned short* bn = Bs[(s + 3) & 3];
#pragma unroll
    for (int ph = 0; ph < 4; ph++) {
      const int ksub = ph >> 1;
      const int th   = ph & 1;
      const int g    = s * 2 + ksub;
      bf16x8 bfv[4];
#pragma unroll
      for (int j = 0; j < 4; j++)
        bfv[j] = *(const bf16x8*)
            &bs[(ksub * 4 + quad) * 1024 + ((th * 4 + j) * 16 + l15) * 8];
      if (s + 3 < 16)
        async_cp16(wb + ((size_t)(s + 3) * 16 + (w + 4 * ph)) * 512 + lane * 8,
                   &bn[(w + 4 * ph) * 512]);
      if ((ph & 1) == 0 && g + 2 < 32) loadA(g + 2, Af[(g + 2) % 3]);
      __builtin_amdgcn_s_barrier();
      asm volatile("s_waitcnt lgkmcnt(0)" ::: "memory");
      __builtin_amdgcn_sched_barrier(0);
      const bf16x8* af = Af[g % 3];
      __builtin_amdgcn_s_setprio(1);
#pragma unroll
      for (int j = 0; j < 4; j++)
#pragma unroll
        for (int tm = 0; tm < 2; tm++)
          acc[tm][th * 4 + j] = __builtin_amdgcn_mfma_f32_16x16x32_bf16(
              af[tm], bfv[j], acc[tm][th * 4 + j], 0, 0, 0);
      __builtin_amdgcn_s_setprio(0);
      __builtin_amdgcn_sched_barrier(0);
      if (ph == 3 && s < 15) {
        if (s <= 12)      asm volatile("s_waitcnt vmcnt(16)" ::: "memory");
        else if (s == 13) asm volatile("s_waitcnt vmcnt(12)" ::: "memory");
        else              asm volatile("s_waitcnt vmcnt(8)"  ::: "memory");
        __builtin_amdgcn_sched_barrier(0);
      }
      __builtin_amdgcn_s_barrier();
    }
  }

#pragma unroll
  for (int tm = 0; tm < 2; tm++)
#pragma unroll
    for (int tn = 0; tn < 8; tn++)
#pragma unroll
      for (int r = 0; r < 4; r++) {
        int row = m0 + w * 32 + tm * 16 + quad * 4 + r;
        int col = n0 + tn * 16 + l15;
        Co[(size_t)row * 1024 + col] = acc[tm][tn][r];
      }
}

// ---------------------------------------------------------------------------
// MFMA sliding-window flash attention (r19, frozen):
// XCD-locality swizzle + V-deferred staging.
// ---------------------------------------------------------------------------
__global__ __launch_bounds__(256, 2)
void attn_mfma(const unsigned short* __restrict__ Qh,
               const unsigned short* __restrict__ Kh,
               const unsigned short* __restrict__ Vt,
               unsigned short* __restrict__ Ypk) {
  __shared__ __align__(16) unsigned short SH[40960];   // 80 KB

  const int tid  = threadIdx.x;
  const int w    = tid >> 6;
  const int lane = tid & 63;
  const int quad = lane >> 4;
  const int l15  = lane & 15;

  // XCD-locality swizzle: hw linear id -> (xcd, slot) -> contiguous v
  const int vid  = blockIdx.y * 32 + blockIdx.x;   // hw dispatch order
  const int v    = (vid & 7) * 256 + (vid >> 3);   // xcd*256 + slot
  const int bh   = v >> 5;                         // 8 bh per XCD
  const int q0   = (v & 31) << 6;

  const int c0 = (q0 >= 256) ? 0 : (4 - (q0 >> 6));

  const unsigned short* Qg = Qh + ((size_t)bh * 2048 + q0) * 64;
  bf16x8 Qf[2];
#pragma unroll
  for (int fs = 0; fs < 2; fs++)
    Qf[fs] = *(const bf16x8*)(Qg + (w * 16 + l15) * 64 + fs * 32 + quad * 8);

  const unsigned short* Kg = Kh + (size_t)bh * 32 * 4096;  // chunk images
  const unsigned short* Vg = Vt + (size_t)bh * 32 * 4096;
  // ---- K first...
  for (int ch = c0; ch < 5; ch++) {
    int tc = (q0 >> 6) - 4 + ch;
#pragma unroll
    for (int i = 0; i < 2; i++) {
      int kc = w * 2 + i;
      async_cp16(Kg + ((size_t)tc * 8 + kc) * 512 + lane * 8,
                 &SH[ch * 4096 + kc * 512]);
    }
  }
  // ---- ...then V (stays in flight across the first barrier)
  for (int ch = c0; ch < 5; ch++) {
    int tc = (q0 >> 6) - 4 + ch;
#pragma unroll
    for (int i = 0; i < 2; i++) {
      int kc = w * 2 + i;
      async_cp16(Vg + ((size_t)tc * 8 + kc) * 512 + lane * 8,
                 &SH[20480 + ch * 4096 + kc * 512]);
    }
  }
  // wait for own Q+K retired, V's 2*(5-c0) ops still outstanding
  if (c0 == 0)      asm volatile("s_waitcnt vmcnt(10)" ::: "memory");
  else if (c0 == 1) asm volatile("s_waitcnt vmcnt(8)"  ::: "memory");
  else if (c0 == 2) asm volatile("s_waitcnt vmcnt(6)"  ::: "memory");
  else if (c0 == 3) asm volatile("s_waitcnt vmcnt(4)"  ::: "memory");
  else              asm volatile("s_waitcnt vmcnt(2)"  ::: "memory");
  __builtin_amdgcn_sched_barrier(0);
  asm volatile("s_barrier" ::: "memory");

  f32x4 S[5][4];
#pragma unroll
  for (int ch = 0; ch < 5; ch++)
#pragma unroll
    for (int tn = 0; tn < 4; tn++) S[ch][tn] = (f32x4)0.0f;

#pragma unroll
  for (int ch = 0; ch < 5; ch++) {
    if (ch < c0) continue;
#pragma unroll
    for (int ks = 0; ks < 2; ks++) {
      int kc = ks * 4 + quad;
#pragma unroll
      for (int tn = 0; tn < 4; tn++) {
        bf16x8 bk = *(const bf16x8*)
            &SH[ch * 4096 + kc * 512 + (tn * 16 + l15) * 8];
        S[ch][tn] = __builtin_amdgcn_mfma_f32_16x16x32_bf16(
            Qf[ks], bk, S[ch][tn], 0, 0, 0);
      }
    }
  }

  const int qb = q0 + w * 16 + quad * 4;
  if (c0 == 0) {
#pragma unroll
    for (int tn = 0; tn < 4; tn++) {
      int j = q0 - 256 + tn * 16 + l15;
#pragma unroll
      for (int r = 0; r < 4; r++)
        if (qb + r > j + (WW - 1)) S[0][tn][r] = -__builtin_inff();
    }
  }
#pragma unroll
  for (int tn = 0; tn < 4; tn++) {
    int j = q0 + tn * 16 + l15;
#pragma unroll
    for (int r = 0; r < 4; r++)
      if (j > qb + r) S[4][tn][r] = -__builtin_inff();
  }

  float mrow[4], lrow[4];
#pragma unroll
  for (int r = 0; r < 4; r++) mrow[r] = -__builtin_inff();
#pragma unroll
  for (int ch = 0; ch < 5; ch++) {
    if (ch < c0) continue;
#pragma unroll
    for (int tn = 0; tn < 4; tn++)
#pragma unroll
      for (int r = 0; r < 4; r++)
        mrow[r] = fmaxf(mrow[r], S[ch][tn][r]);
  }
#pragma unroll
  for (int off = 1; off < 16; off <<= 1)
#pragma unroll
    for (int r = 0; r < 4; r++)
      mrow[r] = fmaxf(mrow[r], __shfl_xor(mrow[r], off));

#pragma unroll
  for (int r = 0; r < 4; r++) lrow[r] = 0.0f;
#pragma unroll
  for (int ch = 0; ch < 5; ch++) {
    if (ch < c0) continue;
#pragma unroll
    for (int tn = 0; tn < 4; tn++)
#pragma unroll
      for (int r = 0; r < 4; r++) {
        float e = __expf(S[ch][tn][r] - mrow[r]);
        S[ch][tn][r] = e;
        lrow[r] += e;
      }
  }
#pragma unroll
  for (int off = 1; off < 16; off <<= 1)
#pragma unroll
    for (int r = 0; r < 4; r++) lrow[r] += __shfl_xor(lrow[r], off);

  // all K-LDS reads done (S in regs); drain own V (hidden under the
  // QK^T+softmax above); then Ps may alias the K region and PV may read V.
  asm volatile("s_waitcnt vmcnt(0)" ::: "memory");
  __builtin_amdgcn_sched_barrier(0);
  asm volatile("s_barrier" ::: "memory");

  f32x4 Oacc[4];
#pragma unroll
  for (int td = 0; td < 4; td++) Oacc[td] = (f32x4)0.0f;

#pragma unroll
  for (int ch = 0; ch < 5; ch++) {
    if (ch < c0) continue;
    unsigned short* Ps = SH + (ch & 1) * 4608;
#pragma unroll
    for (int tn = 0; tn < 4; tn++)
#pragma unroll
      for (int r = 0; r < 4; r++)
        Ps[(w * 16 + quad * 4 + r) * 68 + tn * 16 + l15] = f2bf(S[ch][tn][r]);
    asm volatile("s_waitcnt lgkmcnt(0)" ::: "memory");
#pragma unroll
    for (int ks = 0; ks < 2; ks++) {
      int off = (w * 16 + l15) * 68 + ks * 32 + quad * 8;
      bf16x4 plo = *(const bf16x4*)&Ps[off];
      bf16x4 phi = *(const bf16x4*)&Ps[off + 4];
      bf16x8 ap = __builtin_shufflevector(plo, phi, 0, 1, 2, 3, 4, 5, 6, 7);
      int kc = ks * 4 + quad;
#pragma unroll
      for (int td = 0; td < 4; td++) {
        bf16x8 bv = *(const bf16x8*)
            &SH[20480 + ch * 4096 + kc * 512 + (td * 16 + l15) * 8];
        Oacc[td] = __builtin_amdgcn_mfma_f32_16x16x32_bf16(
            ap, bv, Oacc[td], 0, 0, 0);
      }
    }
  }

  const int b = bh >> 4, h = bh & 15;
  float inv[4];
#pragma unroll
  for (int r = 0; r < 4; r++) inv[r] = 1.0f / lrow[r];
  unsigned short* Ot = SH + 10240;
#pragma unroll
  for (int td = 0; td < 4; td++)
#pragma unroll
    for (int r = 0; r < 4; r++)
      Ot[(w * 16 + quad * 4 + r) * 72 + td * 16 + l15] =
          f2bf(Oacc[td][r] * inv[r]);
  asm volatile("s_waitcnt lgkmcnt(0)" ::: "memory");
  const size_t rt = (size_t)((b * 2048 + q0) >> 4) + w;
#pragma unroll
  for (int f = 0; f < 2; f++) {
    bf16x8 fr = *(const bf16x8*)&Ot[(w * 16 + l15) * 72 + f * 32 + quad * 8];
    *(bf16x8*)&Ypk[(rt * 32 + h * 2 + f) * 512 + lane * 8] = fr;
  }
}

// ---------------------------------------------------------------------------
extern "C" void kernel_launch(void* const* d_in, const int* in_sizes, int n_in,
                              void* d_out, int out_size, void* d_ws, size_t ws_size,
                              hipStream_t stream) {
  const float* x     = (const float*)d_in[0];
  const float* wqkv  = (const float*)d_in[1];
  const float* wproj = (const float*)d_in[2];
  float* out = (float*)d_out;

  char* ws = (char*)d_ws;
  // [0,16M)   Apk (packed x)
  // [16,22M)  Wqkv packed bf16   [22,24M) Wproj packed bf16
  // [24,40M)  Qh   [40,56M) Kpk   [56,72M) Vpk   [72,88M) Ypk (packed y)
  unsigned short* apk    = (unsigned short*)(ws);
  unsigned short* wqkvb  = (unsigned short*)(ws + (size_t)16 * 1024 * 1024);
  unsigned short* wprojb = (unsigned short*)(ws + (size_t)22 * 1024 * 1024);
  unsigned short* qh     = (unsigned short*)(ws + (size_t)24 * 1024 * 1024);
  unsigned short* kh     = (unsigned short*)(ws + (size_t)40 * 1024 * 1024);
  unsigned short* vt     = (unsigned short*)(ws + (size_t)56 * 1024 * 1024);
  unsigned short* ypk    = (unsigned short*)(ws + (size_t)72 * 1024 * 1024);

  prep<<<4096 + 2048, 256, 0, stream>>>(x, wqkv, wproj, wqkvb, apk);

  // qkv = x @ Wqkv^T -> Qh (head-major) + Kpk/Vpk (attn chunk-images)
  gemm_qkv<<<768, 256, 0, stream>>>(apk, wqkvb, qh, kh, vt);

  attn_mfma<<<dim3(TT / 64, BB * HH), 256, 0, stream>>>(
      qh, kh, vt, ypk);

  gemm_proj<<<512, 256, 0, stream>>>(ypk, wprojb, out);
}

// Round 10
// 198.130 us; speedup vs baseline: 1.0123x; 1.0123x over previous
//
#include <hip/hip_runtime.h>
#include <hip/hip_bf16.h>
#include <math.h>

// Problem constants
#define BB 4
#define TT 2048
#define CC 1024
#define HH 16
#define DD 64
#define WW 256
#define MM (BB*TT)   // 8192 rows
#define NX (MM*CC)
#define NQ (3*CC*CC)
#define NP (CC*CC)

typedef __bf16 bf16x8 __attribute__((ext_vector_type(8)));
typedef __bf16 bf16x4 __attribute__((ext_vector_type(4)));
typedef float  f32x4  __attribute__((ext_vector_type(4)));

// async global->LDS 16B. LDS dest: wave-uniform base, HW adds lane*16.
// GLOBAL SOURCE IS PER-LANE: caller must add lane*16B for a contiguous
// stage (r17 lesson).
__device__ __forceinline__ void async_cp16(const void* g, void* l) {
  __builtin_amdgcn_global_load_lds(
      (const __attribute__((address_space(1))) void*)g,
      (__attribute__((address_space(3))) void*)l, 16, 0, 0);
}

__device__ __forceinline__ unsigned short f2bf(float v) {
  __hip_bfloat16 h = __float2bfloat16(v);
  return *(unsigned short*)&h;
}

// Weight chunk-image pack offset: layout
//   [panel p = n>>7][ktile kt = k>>6][chunk = kc*2+half][lane = n&63][ko = k&7]
// gemm stage cp16 #idx reads 1KB CONTIGUOUS (lane l -> +16B*l) at
// ((p*16+kt)*16+idx)*512.
__device__ __forceinline__ size_t wpk_off(int n, int k) {
  return ((((size_t)(n >> 7) * 16 + (k >> 6)) * 16) +
          (((k >> 3) & 7) * 2 + ((n >> 6) & 1))) * 512 +
         (size_t)(n & 63) * 8 + (k & 7);
}

// ---------------------------------------------------------------------------
// prep: fused (a) weight fp32->bf16 convert + chunk-image pack,
// (b) x convert+pack into MFMA A-fragment-major layout.
// ---------------------------------------------------------------------------
__global__ __launch_bounds__(256)
void prep(const float* __restrict__ x,
          const float* __restrict__ wq,
          const float* __restrict__ wp,
          unsigned short* __restrict__ wpk,
          unsigned short* __restrict__ Apk) {
  const int p = blockIdx.x;
  const int tid = threadIdx.x;
  if (p < 4096) {                       // ---- weight convert + pack
    int i = (p * 256 + tid) * 4;
    const float* src; unsigned short* dst; int n, k;
    if (i < NQ) { src = wq + i; n = i >> 10; k = i & 1023; dst = wpk; }
    else {
      int j = i - NQ;
      src = wp + j; n = j >> 10; k = j & 1023; dst = wpk + NQ;
    }
    float4 v = *(const float4*)src;
    size_t off = wpk_off(n, k);         // k%4==0 -> 4 shorts contiguous
    dst[off + 0] = f2bf(v.x);
    dst[off + 1] = f2bf(v.y);
    dst[off + 2] = f2bf(v.z);
    dst[off + 3] = f2bf(v.w);
    return;
  }
  // ---- x convert + pack (64 rows x 64 k per block)
  __shared__ __align__(16) unsigned short tile[64 * 72]; // stride 144B
  const int pid = p - 4096;
  const int bm = pid & 127;
  const int bk = pid >> 7;
  const int tr = tid >> 4;
  const int tc = (tid & 15) * 4;
#pragma unroll
  for (int i = 0; i < 4; i++) {
    int row = i * 16 + tr;
    float4 v = *(const float4*)&x[(size_t)(bm * 64 + row) * 1024 + bk * 64 + tc];
    tile[row * 72 + tc + 0] = f2bf(v.x);
    tile[row * 72 + tc + 1] = f2bf(v.y);
    tile[row * 72 + tc + 2] = f2bf(v.z);
    tile[row * 72 + tc + 3] = f2bf(v.w);
  }
  __syncthreads();
  const int w = tid >> 6, lane = tid & 63;
  const int quad = lane >> 4, l15 = lane & 15;
#pragma unroll
  for (int f = 0; f < 2; f++) {
    bf16x8 fr = *(const bf16x8*)&tile[(w * 16 + l15) * 72 + f * 32 + quad * 8];
    *(bf16x8*)&Apk[(((size_t)(bm * 4 + w) * 32) + bk * 2 + f) * 512 + lane * 8] = fr;
  }
}

// ---------------------------------------------------------------------------
// QKV GEMM (r18 form, frozen at ~56us in-run = the 2-barrier-structure
// ceiling; r21 fine-phase "78us" shown to be a profiling artifact).
// ---------------------------------------------------------------------------
__global__ __launch_bounds__(256, 2)
void gemm_qkv(const unsigned short* __restrict__ Apk,
              const unsigned short* __restrict__ Bw,
              unsigned short* __restrict__ Qh,
              unsigned short* __restrict__ Kh,
              unsigned short* __restrict__ Vt) {
  __shared__ __align__(16) unsigned short Bs[4][8192]; // 4 x 16 KB, BK=64

  const int id   = blockIdx.x;
  const int xcd  = id & 7;
  const int slot = id >> 3;        // 0..95
  const int mloc = slot / 24;      // 0..3   (XCD-local m-block)
  const int nloc = slot % 24;      // 0..23  (n-panels stream over L2-hot A)
  const int m0 = (xcd * 4 + mloc) * 256;
  const int n0 = nloc * 128;

  const int tid  = threadIdx.x;
  const int w    = tid >> 6;       // 0..3: row-block of 64
  const int lane = tid & 63;
  const int quad = lane >> 4;
  const int l15  = lane & 15;

  f32x4 acc[4][8];
#pragma unroll
  for (int i = 0; i < 4; i++)
#pragma unroll
    for (int j = 0; j < 8; j++) acc[i][j] = (f32x4)0.0f;

  const unsigned short* abase =
      Apk + ((size_t)((m0 >> 4) + w * 4) * 32) * 512 + lane * 8;

  // packed-panel base: panel p = n0>>7, 16 ktiles x 16 chunks x 512
  const unsigned short* wb = Bw + (size_t)(n0 >> 7) * (16 * 16 * 512);

  // BK=64 stage: 16 KB/buffer -> 4 cp16/wave, contiguous 1KB each
  auto stageB = [&](int kt, unsigned short* bs) {
#pragma unroll
    for (int i = 0; i < 4; i++) {
      int idx = w + 4 * i;         // 0..15
      async_cp16(wb + ((size_t)kt * 16 + idx) * 512 + lane * 8,
                 &bs[idx * 512]);
    }
  };

  bf16x8 Af[3][4];                 // depth-2 A prefetch ring (L2-hit ~200cyc)
  auto loadA = [&](int g, bf16x8* fr) {
#pragma unroll
    for (int tm = 0; tm < 4; tm++)
      fr[tm] = *(const bf16x8*)(abase + ((size_t)(tm * 32 + g)) * 512);
  };

  // prologue: A for g=0,1; stage buffers 0..2; one-time full drain
  loadA(0, Af[0]);
  loadA(1, Af[1]);
  stageB(0, Bs[0]);
  stageB(1, Bs[1]);
  stageB(2, Bs[2]);
  asm volatile("s_waitcnt vmcnt(0)" ::: "memory");
  __builtin_amdgcn_sched_barrier(0);
  asm volatile("s_barrier" ::: "memory");

#pragma unroll
  for (int s = 0; s < 16; s++) {
    const unsigned short* bs = Bs[s & 3];
    if (s + 3 < 16) stageB(s + 3, Bs[(s + 3) & 3]); // 3-deep prefetch
#pragma unroll
    for (int sub = 0; sub < 2; sub++) {
      const int g = s * 2 + sub;
      if (g + 2 < 32) loadA(g + 2, Af[(g + 2) % 3]);
      const bf16x8* af = Af[g % 3];
      __builtin_amdgcn_s_setprio(1);
#pragma unroll
      for (int tn = 0; tn < 8; tn++) {
        bf16x8 bfv = *(const bf16x8*)
            &bs[(sub * 4 + quad) * 1024 + (tn * 16 + l15) * 8];
#pragma unroll
        for (int tm = 0; tm < 4; tm++)
          acc[tm][tn] = __builtin_amdgcn_mfma_f32_16x16x32_bf16(
              af[tm], bfv, acc[tm][tn], 0, 0, 0);
      }
      __builtin_amdgcn_s_setprio(0);
    }
    // publish stage(s+1) retirement (counted; stages s+2,s+3 + A stay
    // in flight across the barrier), drain own ds_reads of Bs[s&3].
    asm volatile("s_waitcnt vmcnt(16) lgkmcnt(0)" ::: "memory");
    __builtin_amdgcn_sched_barrier(0);
    asm volatile("s_barrier" ::: "memory");
  }

  const int t3 = n0 >> 10;              // block-uniform: 0=Q,1=K,2=V
  if (t3 == 0) {
    // ---- Q scatter to head-major [b*h][t][d] (attn reads directly)
#pragma unroll
    for (int tm = 0; tm < 4; tm++)
#pragma unroll
      for (int tn = 0; tn < 8; tn++) {
        int colb = n0 + tn * 16;
        int hh = (colb >> 6) & 15;
        int dd = (colb & 63) + l15;
#pragma unroll
        for (int r = 0; r < 4; r++) {
          int row = m0 + w * 64 + tm * 16 + quad * 4 + r;
          int b = row >> 11, tt = row & 2047;
          Qh[((size_t)((b * 16 + hh) * 2048 + tt)) * 64 + dd] =
              f2bf(acc[tm][tn][r] * 0.125f);   // 1/sqrt(64)
        }
      }
  } else if (t3 == 1) {
    // ---- K scatter to chunk-image Kpk[bh][tc][d-octet][tin][8]
#pragma unroll
    for (int tm = 0; tm < 4; tm++)
#pragma unroll
      for (int tn = 0; tn < 8; tn++) {
        int colb = n0 + tn * 16;
        int hh = (colb >> 6) & 15;
        int dd = (colb & 63) + l15;
#pragma unroll
        for (int r = 0; r < 4; r++) {
          int row = m0 + w * 64 + tm * 16 + quad * 4 + r;
          int b = row >> 11, tt = row & 2047;
          Kh[((((size_t)(b * 16 + hh) * 32 + (tt >> 6)) * 8 + (dd >> 3)) * 512)
             + (tt & 63) * 8 + (dd & 7)] = f2bf(acc[tm][tn][r]);
        }
      }
  } else {
    // ---- V: per-wave LDS transpose -> Vpk[bh][tc][t-octet][d][8t]
    unsigned short* T = &Bs[0][0] + w * 4608;            // 64x72 tile/wave
    const int b    = (m0 + w * 64) >> 11;
    const int tc_g = ((m0 & 2047) >> 6) + w;
    const int h0   = (n0 >> 6) & 15;
#pragma unroll
    for (int hp = 0; hp < 2; hp++) {
      // T[d][t^]: T[d*72 + t^] = V value at (t = chunk*64 + t^, d)
#pragma unroll
      for (int tnl = 0; tnl < 4; tnl++)
#pragma unroll
        for (int tm = 0; tm < 4; tm++)
#pragma unroll
          for (int r = 0; r < 4; r++)
            T[(tnl * 16 + l15) * 72 + tm * 16 + quad * 4 + r] =
                f2bf(acc[tm][hp * 4 + tnl][r]);
      asm volatile("s_waitcnt lgkmcnt(0)" ::: "memory");  // wave-private
      const size_t base =
          ((size_t)((b * 16 + h0 + hp) * 32 + tc_g)) * 4096;
#pragma unroll
      for (int j = 0; j < 8; j++) {                       // t-octet
        bf16x8 v = *(const bf16x8*)&T[lane * 72 + j * 8]; // d=lane
        *(bf16x8*)&Vt[base + (size_t)j * 512 + lane * 8] = v; // 1KB contig
      }
    }
  }
}

// ---------------------------------------------------------------------------
// Proj GEMM (r21 fine-phase, kept: ~+3us real gain).
// ---------------------------------------------------------------------------
__global__ __launch_bounds__(256, 2)
void gemm_proj(const unsigned short* __restrict__ Apk,
               const unsigned short* __restrict__ Bw,
               float* __restrict__ Co) {
  __shared__ __align__(16) unsigned short Bs[4][8192];

  const int id   = blockIdx.x;
  const int xcd  = id & 7;
  const int slot = id >> 3;        // 0..63
  const int mloc = slot >> 3;      // 0..7
  const int nloc = slot & 7;       // 0..7
  const int m0 = (xcd * 8 + mloc) * 128;
  const int n0 = nloc * 128;

  const int tid  = threadIdx.x;
  const int w    = tid >> 6;
  const int lane = tid & 63;
  const int quad = lane >> 4;
  const int l15  = lane & 15;

  f32x4 acc[2][8];
#pragma unroll
  for (int i = 0; i < 2; i++)
#pragma unroll
    for (int j = 0; j < 8; j++) acc[i][j] = (f32x4)0.0f;

  const unsigned short* abase =
      Apk + ((size_t)((m0 >> 4) + w * 2) * 32) * 512 + lane * 8;

  const unsigned short* wb = Bw + (size_t)(n0 >> 7) * (16 * 16 * 512);

  auto stageB = [&](int kt, unsigned short* bs) {
#pragma unroll
    for (int i = 0; i < 4; i++) {
      int idx = w + 4 * i;
      async_cp16(wb + ((size_t)kt * 16 + idx) * 512 + lane * 8,
                 &bs[idx * 512]);
    }
  };

  bf16x8 Af[3][2];                 // depth-2 A prefetch ring
  auto loadA = [&](int g, bf16x8* fr) {
#pragma unroll
    for (int tm = 0; tm < 2; tm++)
      fr[tm] = *(const bf16x8*)(abase + ((size_t)(tm * 32 + g)) * 512);
  };

  stageB(0, Bs[0]);
  stageB(1, Bs[1]);
  stageB(2, Bs[2]);
  loadA(0, Af[0]);
  loadA(1, Af[1]);
  asm volatile("s_waitcnt vmcnt(12)" ::: "memory");
  __builtin_amdgcn_sched_barrier(0);
  __builtin_amdgcn_s_barrier();

#pragma unroll
  for (int s = 0; s < 16; s++) {
    const unsigned short* bs = Bs[s & 3];
    unsigned short* bn = Bs[(s + 3) & 3];
#pragma unroll
    for (int ph = 0; ph < 4; ph++) {
      const int ksub = ph >> 1;
      const int th   = ph & 1;
      const int g    = s * 2 + ksub;
      bf16x8 bfv[4];
#pragma unroll
      for (int j = 0; j < 4; j++)
        bfv[j] = *(const bf16x8*)
            &bs[(ksub * 4 + quad) * 1024 + ((th * 4 + j) * 16 + l15) * 8];
      if (s + 3 < 16)
        async_cp16(wb + ((size_t)(s + 3) * 16 + (w + 4 * ph)) * 512 + lane * 8,
                   &bn[(w + 4 * ph) * 512]);
      if ((ph & 1) == 0 && g + 2 < 32) loadA(g + 2, Af[(g + 2) % 3]);
      __builtin_amdgcn_s_barrier();
      asm volatile("s_waitcnt lgkmcnt(0)" ::: "memory");
      __builtin_amdgcn_sched_barrier(0);
      const bf16x8* af = Af[g % 3];
      __builtin_amdgcn_s_setprio(1);
#pragma unroll
      for (int j = 0; j < 4; j++)
#pragma unroll
        for (int tm = 0; tm < 2; tm++)
          acc[tm][th * 4 + j] = __builtin_amdgcn_mfma_f32_16x16x32_bf16(
              af[tm], bfv[j], acc[tm][th * 4 + j], 0, 0, 0);
      __builtin_amdgcn_s_setprio(0);
      __builtin_amdgcn_sched_barrier(0);
      if (ph == 3 && s < 15) {
        if (s <= 12)      asm volatile("s_waitcnt vmcnt(16)" ::: "memory");
        else if (s == 13) asm volatile("s_waitcnt vmcnt(12)" ::: "memory");
        else              asm volatile("s_waitcnt vmcnt(8)"  ::: "memory");
        __builtin_amdgcn_sched_barrier(0);
      }
      __builtin_amdgcn_s_barrier();
    }
  }

#pragma unroll
  for (int tm = 0; tm < 2; tm++)
#pragma unroll
    for (int tn = 0; tn < 8; tn++)
#pragma unroll
      for (int r = 0; r < 4; r++) {
        int row = m0 + w * 32 + tm * 16 + quad * 4 + r;
        int col = n0 + tn * 16 + l15;
        Co[(size_t)row * 1024 + col] = acc[tm][tn][r];
      }
}

// ---------------------------------------------------------------------------
// attn (round 23): STREAMING K/V -> LDS 80KB->49KB -> 3 blocks/CU.
// Theory: attn was occupancy-bound (2 blk/CU = 2 waves/SIMD) because all
// 5 K + 5 V chunks were resident at once; but both QK^T and PV consume
// chunks SEQUENTIALLY. K streams through a 2-slot ring (restage ch+2
// after QK^T(ch)+barrier); V through a 3-slot ring (V0-2 upfront, V3/V4
// restaged after PV(0)/PV(1)+barrier). Ps/Ot in a separate region (no
// K-alias -> old pre-PV full drain gone). c0-blocks CLAMP their staging
// chunk index (reads valid chunk-0 data, discarded) so per-wave issue
// counts are block-uniform -> constant vmcnt derivations:
//  issue order/wave: Qf(2) K0(2) K1(2) V0(2) V1(2) V2(2) | K2 | K3 | K4
//  QK entry: ch0/1 vmcnt(8); ch2/3 vmcnt(2); ch4 vmcnt(0) [drains V0-2]
//  PV entry: ch3 vmcnt(2) [V4 flying]; ch4 vmcnt(0); each + s_barrier
//  (per-wave wait publishes OWN cp16s; barrier joins all waves').
// LDS: K[2]@0, V[3]@8192, Ps/Ot(stride 68, wave-private rows)@20480;
// total 25088 shorts = 49KB <= 160/3.
// ---------------------------------------------------------------------------
__global__ __launch_bounds__(256, 2)
void attn_mfma(const unsigned short* __restrict__ Qh,
               const unsigned short* __restrict__ Kh,
               const unsigned short* __restrict__ Vt,
               unsigned short* __restrict__ Ypk) {
  __shared__ __align__(16) unsigned short SH[25088];   // 49 KB

  const int tid  = threadIdx.x;
  const int w    = tid >> 6;
  const int lane = tid & 63;
  const int quad = lane >> 4;
  const int l15  = lane & 15;

  // XCD-locality swizzle (r19): 8 bh per XCD, q-chunks contiguous
  const int vid  = blockIdx.y * 32 + blockIdx.x;
  const int v    = (vid & 7) * 256 + (vid >> 3);
  const int bh   = v >> 5;
  const int q0   = (v & 31) << 6;
  const int c0 = (q0 >= 256) ? 0 : (4 - (q0 >> 6));

  const unsigned short* Qg = Qh + ((size_t)bh * 2048 + q0) * 64;
  bf16x8 Qf[2];
#pragma unroll
  for (int fs = 0; fs < 2; fs++)
    Qf[fs] = *(const bf16x8*)(Qg + (w * 16 + l15) * 64 + fs * 32 + quad * 8);
  __builtin_amdgcn_sched_barrier(0);

  const unsigned short* Kg = Kh + (size_t)bh * 32 * 4096;  // chunk images
  const unsigned short* Vg = Vt + (size_t)bh * 32 * 4096;

  auto tcc = [&](int ch) { int t = (q0 >> 6) - 4 + ch; return t < 0 ? 0 : t; };
  auto stageK = [&](int ch) {
    int t = tcc(ch);
#pragma unroll
    for (int i = 0; i < 2; i++) {
      int kc = w * 2 + i;
      async_cp16(Kg + ((size_t)t * 8 + kc) * 512 + lane * 8,
                 &SH[(ch & 1) * 4096 + kc * 512]);
    }
  };
  auto stageV = [&](int ch) {
    int t = tcc(ch);
#pragma unroll
    for (int i = 0; i < 2; i++) {
      int kc = w * 2 + i;
      async_cp16(Vg + ((size_t)t * 8 + kc) * 512 + lane * 8,
                 &SH[8192 + (ch % 3) * 4096 + kc * 512]);
    }
  };

  stageK(0); stageK(1);
  stageV(0); stageV(1); stageV(2);
  __builtin_amdgcn_sched_barrier(0);

  f32x4 S[5][4];
#pragma unroll
  for (int ch = 0; ch < 5; ch++)
#pragma unroll
    for (int tn = 0; tn < 4; tn++) S[ch][tn] = (f32x4)0.0f;

  // ---- QK^T streaming over K ring
#pragma unroll
  for (int ch = 0; ch < 5; ch++) {
    if (ch <= 1)      asm volatile("s_waitcnt vmcnt(8)" ::: "memory");
    else if (ch <= 3) asm volatile("s_waitcnt vmcnt(2)" ::: "memory");
    else              asm volatile("s_waitcnt vmcnt(0)" ::: "memory");
    __builtin_amdgcn_sched_barrier(0);
    __builtin_amdgcn_s_barrier();          // all waves' K(ch) landed
    if (ch >= c0) {
#pragma unroll
      for (int ks = 0; ks < 2; ks++) {
        int kc = ks * 4 + quad;
#pragma unroll
        for (int tn = 0; tn < 4; tn++) {
          bf16x8 bk = *(const bf16x8*)
              &SH[(ch & 1) * 4096 + kc * 512 + (tn * 16 + l15) * 8];
          S[ch][tn] = __builtin_amdgcn_mfma_f32_16x16x32_bf16(
              Qf[ks], bk, S[ch][tn], 0, 0, 0);
        }
      }
    }
    asm volatile("s_waitcnt lgkmcnt(0)" ::: "memory");  // own reads done
    __builtin_amdgcn_sched_barrier(0);
    __builtin_amdgcn_s_barrier();          // all waves done with slot ch&1
    if (ch + 2 <= 4) { stageK(ch + 2); __builtin_amdgcn_sched_barrier(0); }
  }

  // ---- masks
  const int qb = q0 + w * 16 + quad * 4;
  if (c0 == 0) {
#pragma unroll
    for (int tn = 0; tn < 4; tn++) {
      int j = q0 - 256 + tn * 16 + l15;
#pragma unroll
      for (int r = 0; r < 4; r++)
        if (qb + r > j + (WW - 1)) S[0][tn][r] = -__builtin_inff();
    }
  }
#pragma unroll
  for (int tn = 0; tn < 4; tn++) {
    int j = q0 + tn * 16 + l15;
#pragma unroll
    for (int r = 0; r < 4; r++)
      if (j > qb + r) S[4][tn][r] = -__builtin_inff();
  }

  // ---- softmax (wave-local: 16-lane reduction groups)
  float mrow[4], lrow[4];
#pragma unroll
  for (int r = 0; r < 4; r++) mrow[r] = -__builtin_inff();
#pragma unroll
  for (int ch = 0; ch < 5; ch++) {
    if (ch < c0) continue;
#pragma unroll
    for (int tn = 0; tn < 4; tn++)
#pragma unroll
      for (int r = 0; r < 4; r++)
        mrow[r] = fmaxf(mrow[r], S[ch][tn][r]);
  }
#pragma unroll
  for (int off = 1; off < 16; off <<= 1)
#pragma unroll
    for (int r = 0; r < 4; r++)
      mrow[r] = fmaxf(mrow[r], __shfl_xor(mrow[r], off));

#pragma unroll
  for (int r = 0; r < 4; r++) lrow[r] = 0.0f;
#pragma unroll
  for (int ch = 0; ch < 5; ch++) {
    if (ch < c0) continue;
#pragma unroll
    for (int tn = 0; tn < 4; tn++)
#pragma unroll
      for (int r = 0; r < 4; r++) {
        float e = __expf(S[ch][tn][r] - mrow[r]);
        S[ch][tn][r] = e;
        lrow[r] += e;
      }
  }
#pragma unroll
  for (int off = 1; off < 16; off <<= 1)
#pragma unroll
    for (int r = 0; r < 4; r++) lrow[r] += __shfl_xor(lrow[r], off);

  // ---- PV streaming over V ring (Ps wave-private rows, no block sync
  // needed for Ps; barriers only guard V-slot reuse)
  f32x4 Oacc[4];
#pragma unroll
  for (int td = 0; td < 4; td++) Oacc[td] = (f32x4)0.0f;
  unsigned short* Ps = SH + 20480;

#pragma unroll
  for (int ch = 0; ch < 5; ch++) {
    if (ch == 3) {                       // V3 landed (V4 still flying)
      asm volatile("s_waitcnt vmcnt(2)" ::: "memory");
      __builtin_amdgcn_sched_barrier(0);
      __builtin_amdgcn_s_barrier();
    } else if (ch == 4) {                // V4 landed
      asm volatile("s_waitcnt vmcnt(0)" ::: "memory");
      __builtin_amdgcn_sched_barrier(0);
      __builtin_amdgcn_s_barrier();
    }
    if (ch >= c0) {
      asm volatile("s_waitcnt lgkmcnt(0)" ::: "memory"); // prior Ps reads done
#pragma unroll
      for (int tn = 0; tn < 4; tn++)
#pragma unroll
        for (int r = 0; r < 4; r++)
          Ps[(w * 16 + quad * 4 + r) * 68 + tn * 16 + l15] = f2bf(S[ch][tn][r]);
      asm volatile("s_waitcnt lgkmcnt(0)" ::: "memory");
      __builtin_amdgcn_sched_barrier(0);
#pragma unroll
      for (int ks = 0; ks < 2; ks++) {
        int off = (w * 16 + l15) * 68 + ks * 32 + quad * 8;
        bf16x4 plo = *(const bf16x4*)&Ps[off];
        bf16x4 phi = *(const bf16x4*)&Ps[off + 4];
        bf16x8 ap = __builtin_shufflevector(plo, phi, 0, 1, 2, 3, 4, 5, 6, 7);
        int kc = ks * 4 + quad;
#pragma unroll
        for (int td = 0; td < 4; td++) {
          bf16x8 bv = *(const bf16x8*)
              &SH[8192 + (ch % 3) * 4096 + kc * 512 + (td * 16 + l15) * 8];
          Oacc[td] = __builtin_amdgcn_mfma_f32_16x16x32_bf16(
              ap, bv, Oacc[td], 0, 0, 0);
        }
      }
    }
    if (ch == 0) {                       // slot 0 free -> restage V3
      asm volatile("s_waitcnt lgkmcnt(0)" ::: "memory");
      __builtin_amdgcn_s_barrier();
      stageV(3); __builtin_amdgcn_sched_barrier(0);
    } else if (ch == 1) {                // slot 1 free -> restage V4
      asm volatile("s_waitcnt lgkmcnt(0)" ::: "memory");
      __builtin_amdgcn_s_barrier();
      stageV(4); __builtin_amdgcn_sched_barrier(0);
    }
  }

  // ---- epilogue: Ot aliases Ps region with SAME stride 68 -> rows stay
  // wave-private (no cross-wave overlap even if waves are skewed).
  const int b = bh >> 4, h = bh & 15;
  float inv[4];
#pragma unroll
  for (int r = 0; r < 4; r++) inv[r] = 1.0f / lrow[r];
  unsigned short* Ot = SH + 20480;
#pragma unroll
  for (int td = 0; td < 4; td++)
#pragma unroll
    for (int r = 0; r < 4; r++)
      Ot[(w * 16 + quad * 4 + r) * 68 + td * 16 + l15] =
          f2bf(Oacc[td][r] * inv[r]);
  asm volatile("s_waitcnt lgkmcnt(0)" ::: "memory");
  const size_t rt = (size_t)((b * 2048 + q0) >> 4) + w;
#pragma unroll
  for (int f = 0; f < 2; f++) {
    bf16x8 fr = *(const bf16x8*)&Ot[(w * 16 + l15) * 68 + f * 32 + quad * 8];
    *(bf16x8*)&Ypk[(rt * 32 + h * 2 + f) * 512 + lane * 8] = fr;
  }
}

// ---------------------------------------------------------------------------
extern "C" void kernel_launch(void* const* d_in, const int* in_sizes, int n_in,
                              void* d_out, int out_size, void* d_ws, size_t ws_size,
                              hipStream_t stream) {
  const float* x     = (const float*)d_in[0];
  const float* wqkv  = (const float*)d_in[1];
  const float* wproj = (const float*)d_in[2];
  float* out = (float*)d_out;

  char* ws = (char*)d_ws;
  // [0,16M)   Apk (packed x)
  // [16,22M)  Wqkv packed bf16   [22,24M) Wproj packed bf16
  // [24,40M)  Qh   [40,56M) Kpk   [56,72M) Vpk   [72,88M) Ypk (packed y)
  unsigned short* apk    = (unsigned short*)(ws);
  unsigned short* wqkvb  = (unsigned short*)(ws + (size_t)16 * 1024 * 1024);
  unsigned short* wprojb = (unsigned short*)(ws + (size_t)22 * 1024 * 1024);
  unsigned short* qh     = (unsigned short*)(ws + (size_t)24 * 1024 * 1024);
  unsigned short* kh     = (unsigned short*)(ws + (size_t)40 * 1024 * 1024);
  unsigned short* vt     = (unsigned short*)(ws + (size_t)56 * 1024 * 1024);
  unsigned short* ypk    = (unsigned short*)(ws + (size_t)72 * 1024 * 1024);

  prep<<<4096 + 2048, 256, 0, stream>>>(x, wqkv, wproj, wqkvb, apk);

  // qkv = x @ Wqkv^T -> Qh (head-major) + Kpk/Vpk (attn chunk-images)
  gemm_qkv<<<768, 256, 0, stream>>>(apk, wqkvb, qh, kh, vt);

  attn_mfma<<<dim3(TT / 64, BB * HH), 256, 0, stream>>>(
      qh, kh, vt, ypk);

  gemm_proj<<<512, 256, 0, stream>>>(ypk, wprojb, out);
}